// Round 3
// baseline (1123.384 us; speedup 1.0000x reference)
//
#include <hip/hip_runtime.h>

#define TOK   8192
#define HD    1024
#define NI    2816
#define NI2   5632
#define NEXP  8
#define MAXROWS 17408   // 16384 + 8*128 worst-case padding

typedef __attribute__((ext_vector_type(8))) short short8;
typedef __attribute__((ext_vector_type(4))) short short4v;
typedef __attribute__((ext_vector_type(4))) float f32x4;

// ---------- helpers ----------
__device__ __forceinline__ float bf2f(short v) {
    union { unsigned u; float f; } c; c.u = ((unsigned)(unsigned short)v) << 16; return c.f;
}
__device__ __forceinline__ short f2bf(float f) {
    union { float f; unsigned u; } c; c.f = f;
    unsigned r = c.u + 0x7fff + ((c.u >> 16) & 1);   // RNE
    return (short)(r >> 16);
}
// async global->LDS, 16B per lane. LDS dest = wave-uniform base + lane*16.
__device__ __forceinline__ void gload16(const short* g, short* l) {
    __builtin_amdgcn_global_load_lds(
        (const __attribute__((address_space(1))) void*)(g),
        (__attribute__((address_space(3))) void*)(l),
        16, 0, 0);
}

// ---------- 0. dtype detect: fp32 read as bf16 has huge exponents ----------
__global__ void detect_kernel(const unsigned short* __restrict__ xs, int* __restrict__ ctrl)
{
    int bad = 0;
    for (int i = threadIdx.x; i < 4096; i += 256) {
        int e = (xs[i] >> 7) & 0xFF;
        if (e >= 137) bad = 1;
    }
    if (bad) atomicOr(&ctrl[31], 1);          // flag=1 -> inputs are fp32
}

// ---------- 0c. weight convert + TRANSPOSE: src [E][rows][cols] -> dst [E][cols][rows] bf16 ----------
// LDS tile stride 66 shorts: column-read bank step = 33 = 1 mod 32 -> ~conflict-free.
__global__ __launch_bounds__(256) void transpose_w_kernel(
    const void* __restrict__ src, short* __restrict__ dst,
    const int* __restrict__ ctrl, int rows, int cols)
{
    const int flag = ctrl[31];
    __shared__ short tile[64][66];
    const long ebase = (long)blockIdx.z * rows * cols;
    const int r0 = blockIdx.y * 64, c0 = blockIdx.x * 64;
    const int lr = threadIdx.x >> 2, lc = (threadIdx.x & 3) * 16;

    if (flag) {
        const float* s = (const float*)src + ebase + (long)(r0 + lr) * cols + c0 + lc;
#pragma unroll
        for (int j = 0; j < 16; j += 4) {
            f32x4 v = *(const f32x4*)(s + j);
            tile[lr][lc + j + 0] = f2bf(v.x);
            tile[lr][lc + j + 1] = f2bf(v.y);
            tile[lr][lc + j + 2] = f2bf(v.z);
            tile[lr][lc + j + 3] = f2bf(v.w);
        }
    } else {
        const short* s = (const short*)src + ebase + (long)(r0 + lr) * cols + c0 + lc;
#pragma unroll
        for (int j = 0; j < 16; j += 8)
            *(short8*)&tile[lr][lc + j] = *(const short8*)(s + j);
    }
    __syncthreads();
    short* d = dst + ebase + (long)(c0 + lr) * rows + r0 + lc;
    short8 o0, o1;
#pragma unroll
    for (int j = 0; j < 8; j++) o0[j] = tile[lc + j][lr];
#pragma unroll
    for (int j = 0; j < 8; j++) o1[j] = tile[lc + 8 + j][lr];
    *(short8*)(d) = o0;
    *(short8*)(d + 8) = o1;
}

// ---------- 1. gating (fused x->bf16 convert): logits -> top2 -> renorm ----------
__global__ __launch_bounds__(256) void gate_kernel(
    const void* __restrict__ xraw, const void* __restrict__ gwraw,
    int* __restrict__ top_i, float* __restrict__ top_w, int* __restrict__ ctrl,
    short* __restrict__ xbf)
{
    const int flag = ctrl[31];
    const int wave = threadIdx.x >> 6, lane = threadIdx.x & 63;
    const int t = blockIdx.x * 4 + wave;
    const float* xf = (const float*)xraw + (long)t * HD;
    const short* xs = (const short*)xraw + (long)t * HD;
    const float* gf = (const float*)gwraw;
    const short* gs = (const short*)gwraw;
    short* xo = xbf + (long)t * HD;
    float acc[NEXP] = {0.f, 0.f, 0.f, 0.f, 0.f, 0.f, 0.f, 0.f};
#pragma unroll
    for (int jj = 0; jj < 4; jj++) {
        const int i = jj * 256 + lane * 4;
        float xv0, xv1, xv2, xv3;
        if (flag) {
            f32x4 v = *(const f32x4*)(xf + i);
            xv0 = v.x; xv1 = v.y; xv2 = v.z; xv3 = v.w;
            short4v o; o.x = f2bf(xv0); o.y = f2bf(xv1); o.z = f2bf(xv2); o.w = f2bf(xv3);
            *(short4v*)(xo + i) = o;
        } else {
            short4v v = *(const short4v*)(xs + i);
            xv0 = bf2f(v.x); xv1 = bf2f(v.y); xv2 = bf2f(v.z); xv3 = bf2f(v.w);
            *(short4v*)(xo + i) = v;
        }
#pragma unroll
        for (int e = 0; e < NEXP; e++) {
            if (flag) {
                f32x4 w = *(const f32x4*)(gf + e * HD + i);
                acc[e] += xv0 * w.x + xv1 * w.y + xv2 * w.z + xv3 * w.w;
            } else {
                short4v w = *(const short4v*)(gs + e * HD + i);
                acc[e] += xv0 * bf2f(w.x) + xv1 * bf2f(w.y) + xv2 * bf2f(w.z) + xv3 * bf2f(w.w);
            }
        }
    }
#pragma unroll
    for (int e = 0; e < NEXP; e++)
        for (int off = 32; off > 0; off >>= 1) acc[e] += __shfl_down(acc[e], off, 64);
    if (lane == 0) {
        int a = 0; float va = acc[0];
#pragma unroll
        for (int e = 1; e < NEXP; e++) if (acc[e] > va) { a = e; va = acc[e]; }
        int b = -1; float vb = -1e30f;
#pragma unroll
        for (int e = 0; e < NEXP; e++) if (e != a && acc[e] > vb) { b = e; vb = acc[e]; }
        float r = __expf(vb - va);
        float wa = 1.f / (1.f + r), wb = r / (1.f + r);
        top_i[2 * t] = a;     top_w[2 * t] = wa;
        top_i[2 * t + 1] = b; top_w[2 * t + 1] = wb;
        atomicAdd(&ctrl[a], 1);
        atomicAdd(&ctrl[b], 1);
    }
}

// ---------- 2. offsets (padded to 128) + pad dummy rows ----------
__global__ void offsets_pad_kernel(int* __restrict__ ctrl,
                                   int* __restrict__ rows_tok, float* __restrict__ rows_w)
{
    __shared__ int soff[NEXP + 1];
    if (threadIdx.x == 0) {
        int off = 0;
        for (int e = 0; e < NEXP; e++) {
            soff[e] = off; ctrl[16 + e] = off;
            off += (ctrl[e] + 127) & ~127;
        }
        soff[NEXP] = off; ctrl[24] = off;
    }
    __syncthreads();
    for (int e = 0; e < NEXP; e++) {
        int c = ctrl[e];
        int start = soff[e], len = soff[e + 1] - soff[e];
        for (int s = c + (int)threadIdx.x; s < len; s += blockDim.x) {
            rows_tok[start + s] = 0;
            rows_w[start + s] = 0.f;
        }
    }
}

// ---------- 3. scatter tokens into expert row lists ----------
__global__ __launch_bounds__(256) void scatter_kernel(
    const int* __restrict__ top_i, const float* __restrict__ top_w,
    int* __restrict__ ctrl, int* __restrict__ rows_tok, float* __restrict__ rows_w)
{
    int t = blockIdx.x * 256 + threadIdx.x;
    if (t >= TOK) return;
#pragma unroll
    for (int k = 0; k < 2; k++) {
        int e = top_i[2 * t + k];
        int pos = atomicAdd(&ctrl[8 + e], 1);
        int row = ctrl[16 + e] + pos;
        rows_tok[row] = t;
        rows_w[row] = top_w[2 * t + k];
    }
}

// ---------- 4. GEMM1: act = silu(x@Wg) * (x@Wu) ----------
// 128 rows x (64 gate + 64 up) cols, BK=64 (half the barrier drains of BK=32),
// global_load_lds staging, XOR-swizzled linear LDS, bijective XCD block swizzle (T1).
__global__ __launch_bounds__(256) void gemm1_kernel(
    const short* __restrict__ xbf, const short* __restrict__ w1T,
    const int* __restrict__ rows_tok, const int* __restrict__ ctrl,
    short* __restrict__ act, int r0base)
{
    // T1: bijective chunked XCD swizzle (m204 formula)
    const int gx = gridDim.x;
    const int nwg = gx * gridDim.y;
    int wg = blockIdx.y * gx + blockIdx.x;
    {
        const int q = nwg >> 3, r = nwg & 7;
        const int xcd = wg & 7, idx = wg >> 3;
        wg = (xcd < r ? xcd * (q + 1) : r * (q + 1) + (xcd - r) * q) + idx;
    }
    const int bx = wg % gx, by = wg / gx;

    const int row0 = r0base + by * 128;
    if (row0 >= ctrl[24]) return;
    int e = 0;
#pragma unroll
    for (int q = 1; q < NEXP; q++) if (row0 >= ctrl[16 + q]) e = q;
    const int i0 = bx * 64;

    __shared__ __align__(16) short As[8192];   // [128 rows][64 k], slot-swizzled
    __shared__ __align__(16) short Bg[4096];   // [64 n][64 k]
    __shared__ __align__(16) short Bu[4096];
    __shared__ int toks[128];

    const int tid = threadIdx.x;
    if (tid < 128) toks[tid] = rows_tok[row0 + tid];
    __syncthreads();

    const int wave = tid >> 6, lane = tid & 63;
    const int lm = lane & 15, lq = lane >> 4;
    const int wm = wave >> 1, wn = wave & 1;

    // staging: issue n covers slot s=n*256+tid -> row s>>3, slot8 s&7.
    // source k-group = slot8 ^ (row&7)  (row&7 == (tid>>3)&7 since 32|n*32)
    const int srow = tid >> 3;
    const int xorOff = (((tid & 7) ^ (srow & 7)) << 3);
    const short* aPtr[4];
#pragma unroll
    for (int n4 = 0; n4 < 4; n4++)
        aPtr[n4] = xbf + (long)toks[n4 * 32 + srow] * HD + xorOff;
    const long wb = (long)e * NI2 * HD;
    const short* gPtr[2];
    const short* uPtr[2];
#pragma unroll
    for (int n2 = 0; n2 < 2; n2++) {
        gPtr[n2] = w1T + wb + (long)(i0 + n2 * 32 + srow) * HD + xorOff;
        uPtr[n2] = w1T + wb + (long)(NI + i0 + n2 * 32 + srow) * HD + xorOff;
    }

    // fragment read offsets (shorts): row r, k-slot kq in [0,8): r*64 + ((kq^(r&7))<<3)
    int aOff[4][2], bOff[2][2];
#pragma unroll
    for (int i = 0; i < 4; i++) {
        const int r = wm * 64 + i * 16 + lm, r7 = r & 7;
#pragma unroll
        for (int kh = 0; kh < 2; kh++)
            aOff[i][kh] = r * 64 + (((lq + 4 * kh) ^ r7) << 3);
    }
#pragma unroll
    for (int nf = 0; nf < 2; nf++) {
        const int n = wn * 32 + nf * 16 + lm, n7 = n & 7;
#pragma unroll
        for (int kh = 0; kh < 2; kh++)
            bOff[nf][kh] = n * 64 + (((lq + 4 * kh) ^ n7) << 3);
    }

    const f32x4 zero = {0.f, 0.f, 0.f, 0.f};
    f32x4 acc[4][4];
#pragma unroll
    for (int i = 0; i < 4; i++)
#pragma unroll
        for (int j = 0; j < 4; j++) acc[i][j] = zero;

    for (int kk = 0; kk < HD; kk += 64) {
#pragma unroll
        for (int n4 = 0; n4 < 4; n4++)
            gload16(aPtr[n4] + kk, As + n4 * 2048 + tid * 8);
#pragma unroll
        for (int n2 = 0; n2 < 2; n2++) {
            gload16(gPtr[n2] + kk, Bg + n2 * 2048 + tid * 8);
            gload16(uPtr[n2] + kk, Bu + n2 * 2048 + tid * 8);
        }
        __syncthreads();
#pragma unroll
        for (int kh = 0; kh < 2; kh++) {
            short8 aF[4], gF[2], uF[2];
#pragma unroll
            for (int i = 0; i < 4; i++) aF[i] = *(const short8*)(As + aOff[i][kh]);
#pragma unroll
            for (int nf = 0; nf < 2; nf++) {
                gF[nf] = *(const short8*)(Bg + bOff[nf][kh]);
                uF[nf] = *(const short8*)(Bu + bOff[nf][kh]);
            }
#pragma unroll
            for (int i = 0; i < 4; i++)
#pragma unroll
                for (int nf = 0; nf < 2; nf++) {
                    acc[i][nf]     = __builtin_amdgcn_mfma_f32_16x16x32_bf16(aF[i], gF[nf], acc[i][nf], 0, 0, 0);
                    acc[i][nf + 2] = __builtin_amdgcn_mfma_f32_16x16x32_bf16(aF[i], uF[nf], acc[i][nf + 2], 0, 0, 0);
                }
        }
        __syncthreads();
    }

    const int arow0 = row0 - r0base + wm * 64 + lq * 4;
#pragma unroll
    for (int i = 0; i < 4; i++) {
#pragma unroll
        for (int nf = 0; nf < 2; nf++) {
            int col = i0 + wn * 32 + nf * 16 + lm;
#pragma unroll
            for (int r = 0; r < 4; r++) {
                float g = acc[i][nf][r], u = acc[i][nf + 2][r];
                float a = (g / (1.f + __expf(-g))) * u;
                act[(long)(arow0 + i * 16 + r) * NI + col] = f2bf(a);
            }
        }
    }
}

// ---------- 5. GEMM2: out += w * (act @ W2), full K (BK=64), scaled atomics ----------
__global__ __launch_bounds__(256) void gemm2_kernel(
    const short* __restrict__ act, const short* __restrict__ w2T,
    const int* __restrict__ rows_tok, const float* __restrict__ rows_w,
    const int* __restrict__ ctrl, float* __restrict__ accum, float* __restrict__ doutf,
    int r0base)
{
    const int gx = gridDim.x;
    const int nwg = gx * gridDim.y;
    int wg = blockIdx.y * gx + blockIdx.x;
    {
        const int q = nwg >> 3, r = nwg & 7;
        const int xcd = wg & 7, idx = wg >> 3;
        wg = (xcd < r ? xcd * (q + 1) : r * (q + 1) + (xcd - r) * q) + idx;
    }
    const int bx = wg % gx, by = wg / gx;

    const int row0 = r0base + by * 128;
    if (row0 >= ctrl[24]) return;
    int e = 0;
#pragma unroll
    for (int q = 1; q < NEXP; q++) if (row0 >= ctrl[16 + q]) e = q;
    const int n0 = bx * 128;

    __shared__ __align__(16) short As[8192];   // [128 rows][64 k]
    __shared__ __align__(16) short Bs[8192];   // [128 n][64 k]
    __shared__ int toks[128];
    __shared__ float rws[128];

    const int tid = threadIdx.x;
    if (tid < 128) { toks[tid] = rows_tok[row0 + tid]; rws[tid] = rows_w[row0 + tid]; }
    __syncthreads();

    const int wave = tid >> 6, lane = tid & 63;
    const int lm = lane & 15, lq = lane >> 4;
    const int wm = wave >> 1, wn = wave & 1;

    const int srow = tid >> 3;
    const int xorOff = (((tid & 7) ^ (srow & 7)) << 3);
    const int arow = row0 - r0base;
    const short* aPtr[4];
    const short* bPtr[4];
    const long wb = (long)e * HD * NI;
#pragma unroll
    for (int n4 = 0; n4 < 4; n4++) {
        aPtr[n4] = act + (long)(arow + n4 * 32 + srow) * NI + xorOff;
        bPtr[n4] = w2T + wb + (long)(n0 + n4 * 32 + srow) * NI + xorOff;
    }

    int aOff[4][2], bOff[4][2];
#pragma unroll
    for (int i = 0; i < 4; i++) {
        const int r = wm * 64 + i * 16 + lm, r7 = r & 7;
        const int n = wn * 64 + i * 16 + lm, n7 = n & 7;
#pragma unroll
        for (int kh = 0; kh < 2; kh++) {
            aOff[i][kh] = r * 64 + (((lq + 4 * kh) ^ r7) << 3);
            bOff[i][kh] = n * 64 + (((lq + 4 * kh) ^ n7) << 3);
        }
    }

    const f32x4 zero = {0.f, 0.f, 0.f, 0.f};
    f32x4 acc[4][4];
#pragma unroll
    for (int i = 0; i < 4; i++)
#pragma unroll
        for (int j = 0; j < 4; j++) acc[i][j] = zero;

    for (int kk = 0; kk < NI; kk += 64) {
#pragma unroll
        for (int n4 = 0; n4 < 4; n4++) {
            gload16(aPtr[n4] + kk, As + n4 * 2048 + tid * 8);
            gload16(bPtr[n4] + kk, Bs + n4 * 2048 + tid * 8);
        }
        __syncthreads();
#pragma unroll
        for (int kh = 0; kh < 2; kh++) {
            short8 aF[4], bF[4];
#pragma unroll
            for (int i = 0; i < 4; i++) {
                aF[i] = *(const short8*)(As + aOff[i][kh]);
                bF[i] = *(const short8*)(Bs + bOff[i][kh]);
            }
#pragma unroll
            for (int i = 0; i < 4; i++)
#pragma unroll
                for (int j = 0; j < 4; j++)
                    acc[i][j] = __builtin_amdgcn_mfma_f32_16x16x32_bf16(aF[i], bF[j], acc[i][j], 0, 0, 0);
        }
        __syncthreads();
    }

    const int flag = ctrl[31];
    float* dst = flag ? doutf : accum;
#pragma unroll
    for (int i = 0; i < 4; i++) {
        int rl = wm * 64 + i * 16 + lq * 4;
#pragma unroll
        for (int r = 0; r < 4; r++) {
            float w = rws[rl + r];
            if (w != 0.f) {
                long tb = (long)toks[rl + r] * HD + n0 + wn * 64 + lm;
#pragma unroll
                for (int j = 0; j < 4; j++)
                    atomicAdd(&dst[tb + j * 16], acc[i][j][r] * w);
            }
        }
    }
}

// ---------- 6. fp32 accum -> bf16 out (bf16 mode only), vectorized ----------
__global__ __launch_bounds__(256) void convert_kernel(
    const float* __restrict__ accum, short* __restrict__ out, const int* __restrict__ ctrl)
{
    if (ctrl[31]) return;   // fp32 mode: gemm2 wrote d_out directly
    int idx = blockIdx.x * 256 + threadIdx.x;
    const float* a = accum + (long)idx * 8;
    f32x4 v0 = *(const f32x4*)a;
    f32x4 v1 = *(const f32x4*)(a + 4);
    short8 o;
    o[0] = f2bf(v0.x); o[1] = f2bf(v0.y); o[2] = f2bf(v0.z); o[3] = f2bf(v0.w);
    o[4] = f2bf(v1.x); o[5] = f2bf(v1.y); o[6] = f2bf(v1.z); o[7] = f2bf(v1.w);
    *(short8*)(out + (long)idx * 8) = o;
}

extern "C" void kernel_launch(void* const* d_in, const int* in_sizes, int n_in,
                              void* d_out, int out_size, void* d_ws, size_t ws_size,
                              hipStream_t stream) {
    char* ws = (char*)d_ws;
    // layout: ctrl | top_i | top_w | rows_tok | rows_w | x_bf | w1T | w2T | accum | act(row-chunk)
    int*   ctrl     = (int*)ws;
    int*   top_i    = (int*)(ws + 512);
    float* top_w    = (float*)(ws + 66048);
    int*   rows_tok = (int*)(ws + 131584);
    float* rows_w   = (float*)(ws + 201216);
    short* xbf      = (short*)(ws + 270848);
    short* w1T      = (short*)(ws + 17048064);    // 92,274,688 B
    short* w2T      = (short*)(ws + 109322752);   // 46,137,344 B
    float* accum    = (float*)(ws + 155460096);   // 33,554,432 B
    short* act      = (short*)(ws + 189014528);   // RC * NI * 2 B

    const long act_off = 189014528L;
    long RC = ((long)ws_size - act_off) / (NI * 2);
    RC &= ~127L;
    if (RC > MAXROWS) RC = MAXROWS;
    if (RC < 128) RC = 128;
    while (RC > 128 && act_off + RC * (NI * 2) > (long)ws_size) RC -= 128;

    hipMemsetAsync(ws, 0, 512, stream);                       // ctrl
    hipMemsetAsync(ws + 155460096, 0, 33554432, stream);      // accum
    hipMemsetAsync(d_out, 0, (size_t)out_size * 2, stream);   // safe for both dtypes

    detect_kernel<<<1, 256, 0, stream>>>((const unsigned short*)d_in[0], ctrl);
    transpose_w_kernel<<<dim3(NI2 / 64, HD / 64, NEXP), 256, 0, stream>>>(d_in[2], w1T, ctrl, HD, NI2);
    transpose_w_kernel<<<dim3(HD / 64, NI / 64, NEXP), 256, 0, stream>>>(d_in[3], w2T, ctrl, NI, HD);
    gate_kernel<<<TOK / 4, 256, 0, stream>>>(d_in[0], d_in[1], top_i, top_w, ctrl, xbf);
    offsets_pad_kernel<<<1, 256, 0, stream>>>(ctrl, rows_tok, rows_w);
    scatter_kernel<<<TOK / 256, 256, 0, stream>>>(top_i, top_w, ctrl, rows_tok, rows_w);

    for (long r0 = 0; r0 < MAXROWS; r0 += RC) {
        long rc = MAXROWS - r0; if (rc > RC) rc = RC;
        gemm1_kernel<<<dim3(NI / 64, rc / 128), 256, 0, stream>>>(
            xbf, w1T, rows_tok, ctrl, act, (int)r0);
        gemm2_kernel<<<dim3(HD / 128, rc / 128), 256, 0, stream>>>(
            act, w2T, rows_tok, rows_w, ctrl, accum, (float*)d_out, (int)r0);
    }
    convert_kernel<<<TOK * HD / 8 / 256, 256, 0, stream>>>(accum, (short*)d_out, ctrl);
}

// Round 4
// 1100.463 us; speedup vs baseline: 1.0208x; 1.0208x over previous
//
#include <hip/hip_runtime.h>

#define TOK   8192
#define HD    1024
#define NI    2816
#define NI2   5632
#define NEXP  8
#define MAXROWS 17408   // 16384 + 8*128 worst-case padding

typedef __attribute__((ext_vector_type(8))) short short8;
typedef __attribute__((ext_vector_type(4))) short short4v;
typedef __attribute__((ext_vector_type(4))) float f32x4;

// ---------- helpers ----------
__device__ __forceinline__ float bf2f(short v) {
    union { unsigned u; float f; } c; c.u = ((unsigned)(unsigned short)v) << 16; return c.f;
}
__device__ __forceinline__ short f2bf(float f) {
    union { float f; unsigned u; } c; c.f = f;
    unsigned r = c.u + 0x7fff + ((c.u >> 16) & 1);   // RNE
    return (short)(r >> 16);
}
// async global->LDS, 16B per lane. LDS dest = wave-uniform base + lane*16.
__device__ __forceinline__ void gload16(const short* g, short* l) {
    __builtin_amdgcn_global_load_lds(
        (const __attribute__((address_space(1))) void*)(g),
        (__attribute__((address_space(3))) void*)(l),
        16, 0, 0);
}

// ---------- 0. dtype detect: fp32 read as bf16 has huge exponents ----------
__global__ void detect_kernel(const unsigned short* __restrict__ xs, int* __restrict__ ctrl)
{
    int bad = 0;
    for (int i = threadIdx.x; i < 4096; i += 256) {
        int e = (xs[i] >> 7) & 0xFF;
        if (e >= 137) bad = 1;
    }
    if (bad) atomicOr(&ctrl[31], 1);          // flag=1 -> inputs are fp32
}

// ---------- 0c. weight convert + TRANSPOSE: src [E][rows][cols] -> dst [E][cols][rows] bf16 ----------
// LDS tile stride 66 shorts: column-read bank step = 33 = 1 mod 32 -> ~conflict-free.
__global__ __launch_bounds__(256) void transpose_w_kernel(
    const void* __restrict__ src, short* __restrict__ dst,
    const int* __restrict__ ctrl, int rows, int cols)
{
    const int flag = ctrl[31];
    __shared__ short tile[64][66];
    const long ebase = (long)blockIdx.z * rows * cols;
    const int r0 = blockIdx.y * 64, c0 = blockIdx.x * 64;
    const int lr = threadIdx.x >> 2, lc = (threadIdx.x & 3) * 16;

    if (flag) {
        const float* s = (const float*)src + ebase + (long)(r0 + lr) * cols + c0 + lc;
#pragma unroll
        for (int j = 0; j < 16; j += 4) {
            f32x4 v = *(const f32x4*)(s + j);
            tile[lr][lc + j + 0] = f2bf(v.x);
            tile[lr][lc + j + 1] = f2bf(v.y);
            tile[lr][lc + j + 2] = f2bf(v.z);
            tile[lr][lc + j + 3] = f2bf(v.w);
        }
    } else {
        const short* s = (const short*)src + ebase + (long)(r0 + lr) * cols + c0 + lc;
#pragma unroll
        for (int j = 0; j < 16; j += 8)
            *(short8*)&tile[lr][lc + j] = *(const short8*)(s + j);
    }
    __syncthreads();
    short* d = dst + ebase + (long)(c0 + lr) * rows + r0 + lc;
    short8 o0, o1;
#pragma unroll
    for (int j = 0; j < 8; j++) o0[j] = tile[lc + j][lr];
#pragma unroll
    for (int j = 0; j < 8; j++) o1[j] = tile[lc + 8 + j][lr];
    *(short8*)(d) = o0;
    *(short8*)(d + 8) = o1;
}

// ---------- 1. gating (fused x->bf16 convert): logits -> top2 -> renorm ----------
__global__ __launch_bounds__(256) void gate_kernel(
    const void* __restrict__ xraw, const void* __restrict__ gwraw,
    int* __restrict__ top_i, float* __restrict__ top_w, int* __restrict__ ctrl,
    short* __restrict__ xbf)
{
    const int flag = ctrl[31];
    const int wave = threadIdx.x >> 6, lane = threadIdx.x & 63;
    const int t = blockIdx.x * 4 + wave;
    const float* xf = (const float*)xraw + (long)t * HD;
    const short* xs = (const short*)xraw + (long)t * HD;
    const float* gf = (const float*)gwraw;
    const short* gs = (const short*)gwraw;
    short* xo = xbf + (long)t * HD;
    float acc[NEXP] = {0.f, 0.f, 0.f, 0.f, 0.f, 0.f, 0.f, 0.f};
#pragma unroll
    for (int jj = 0; jj < 4; jj++) {
        const int i = jj * 256 + lane * 4;
        float xv0, xv1, xv2, xv3;
        if (flag) {
            f32x4 v = *(const f32x4*)(xf + i);
            xv0 = v.x; xv1 = v.y; xv2 = v.z; xv3 = v.w;
            short4v o; o.x = f2bf(xv0); o.y = f2bf(xv1); o.z = f2bf(xv2); o.w = f2bf(xv3);
            *(short4v*)(xo + i) = o;
        } else {
            short4v v = *(const short4v*)(xs + i);
            xv0 = bf2f(v.x); xv1 = bf2f(v.y); xv2 = bf2f(v.z); xv3 = bf2f(v.w);
            *(short4v*)(xo + i) = v;
        }
#pragma unroll
        for (int e = 0; e < NEXP; e++) {
            if (flag) {
                f32x4 w = *(const f32x4*)(gf + e * HD + i);
                acc[e] += xv0 * w.x + xv1 * w.y + xv2 * w.z + xv3 * w.w;
            } else {
                short4v w = *(const short4v*)(gs + e * HD + i);
                acc[e] += xv0 * bf2f(w.x) + xv1 * bf2f(w.y) + xv2 * bf2f(w.z) + xv3 * bf2f(w.w);
            }
        }
    }
#pragma unroll
    for (int e = 0; e < NEXP; e++)
        for (int off = 32; off > 0; off >>= 1) acc[e] += __shfl_down(acc[e], off, 64);
    if (lane == 0) {
        int a = 0; float va = acc[0];
#pragma unroll
        for (int e = 1; e < NEXP; e++) if (acc[e] > va) { a = e; va = acc[e]; }
        int b = -1; float vb = -1e30f;
#pragma unroll
        for (int e = 0; e < NEXP; e++) if (e != a && acc[e] > vb) { b = e; vb = acc[e]; }
        float r = __expf(vb - va);
        float wa = 1.f / (1.f + r), wb = r / (1.f + r);
        top_i[2 * t] = a;     top_w[2 * t] = wa;
        top_i[2 * t + 1] = b; top_w[2 * t + 1] = wb;
        atomicAdd(&ctrl[a], 1);
        atomicAdd(&ctrl[b], 1);
    }
}

// ---------- 2. offsets (padded to 128) + pad dummy rows ----------
__global__ void offsets_pad_kernel(int* __restrict__ ctrl,
                                   int* __restrict__ rows_tok, float* __restrict__ rows_w)
{
    __shared__ int soff[NEXP + 1];
    if (threadIdx.x == 0) {
        int off = 0;
        for (int e = 0; e < NEXP; e++) {
            soff[e] = off; ctrl[16 + e] = off;
            off += (ctrl[e] + 127) & ~127;
        }
        soff[NEXP] = off; ctrl[24] = off;
    }
    __syncthreads();
    for (int e = 0; e < NEXP; e++) {
        int c = ctrl[e];
        int start = soff[e], len = soff[e + 1] - soff[e];
        for (int s = c + (int)threadIdx.x; s < len; s += blockDim.x) {
            rows_tok[start + s] = 0;
            rows_w[start + s] = 0.f;
        }
    }
}

// ---------- 3. scatter tokens into expert row lists (+ inverse map tok2row) ----------
__global__ __launch_bounds__(256) void scatter_kernel(
    const int* __restrict__ top_i, const float* __restrict__ top_w,
    int* __restrict__ ctrl, int* __restrict__ rows_tok, float* __restrict__ rows_w,
    int* __restrict__ tok2row)
{
    int t = blockIdx.x * 256 + threadIdx.x;
    if (t >= TOK) return;
#pragma unroll
    for (int k = 0; k < 2; k++) {
        int e = top_i[2 * t + k];
        int pos = atomicAdd(&ctrl[8 + e], 1);
        int row = ctrl[16 + e] + pos;
        rows_tok[row] = t;
        rows_w[row] = top_w[2 * t + k];
        tok2row[2 * t + k] = row;
    }
}

// ---------- 4. GEMM1: act = silu(x@Wg) * (x@Wu) ----------
// 128 rows x (64 gate + 64 up) cols, BK=64, global_load_lds staging,
// XOR-swizzled linear LDS. (T1 XCD swizzle reverted: weights are L3-fit,
// chunked ordering doubled FETCH_SIZE in R3 with zero time gain.)
__global__ __launch_bounds__(256) void gemm1_kernel(
    const short* __restrict__ xbf, const short* __restrict__ w1T,
    const int* __restrict__ rows_tok, const int* __restrict__ ctrl,
    short* __restrict__ act, int r0base)
{
    const int row0 = r0base + blockIdx.y * 128;
    if (row0 >= ctrl[24]) return;
    int e = 0;
#pragma unroll
    for (int q = 1; q < NEXP; q++) if (row0 >= ctrl[16 + q]) e = q;
    const int i0 = blockIdx.x * 64;

    __shared__ __align__(16) short As[8192];   // [128 rows][64 k], slot-swizzled
    __shared__ __align__(16) short Bg[4096];   // [64 n][64 k]
    __shared__ __align__(16) short Bu[4096];
    __shared__ int toks[128];

    const int tid = threadIdx.x;
    if (tid < 128) toks[tid] = rows_tok[row0 + tid];
    __syncthreads();

    const int wave = tid >> 6, lane = tid & 63;
    const int lm = lane & 15, lq = lane >> 4;
    const int wm = wave >> 1, wn = wave & 1;

    // staging: issue n covers slot s=n*256+tid -> row s>>3, slot8 s&7.
    // source k-group = slot8 ^ (row&7)  (row&7 == (tid>>3)&7 since 32|n*32)
    const int srow = tid >> 3;
    const int xorOff = (((tid & 7) ^ (srow & 7)) << 3);
    const short* aPtr[4];
#pragma unroll
    for (int n4 = 0; n4 < 4; n4++)
        aPtr[n4] = xbf + (long)toks[n4 * 32 + srow] * HD + xorOff;
    const long wb = (long)e * NI2 * HD;
    const short* gPtr[2];
    const short* uPtr[2];
#pragma unroll
    for (int n2 = 0; n2 < 2; n2++) {
        gPtr[n2] = w1T + wb + (long)(i0 + n2 * 32 + srow) * HD + xorOff;
        uPtr[n2] = w1T + wb + (long)(NI + i0 + n2 * 32 + srow) * HD + xorOff;
    }

    // fragment read offsets (shorts): row r, k-slot kq in [0,8): r*64 + ((kq^(r&7))<<3)
    int aOff[4][2], bOff[2][2];
#pragma unroll
    for (int i = 0; i < 4; i++) {
        const int r = wm * 64 + i * 16 + lm, r7 = r & 7;
#pragma unroll
        for (int kh = 0; kh < 2; kh++)
            aOff[i][kh] = r * 64 + (((lq + 4 * kh) ^ r7) << 3);
    }
#pragma unroll
    for (int nf = 0; nf < 2; nf++) {
        const int n = wn * 32 + nf * 16 + lm, n7 = n & 7;
#pragma unroll
        for (int kh = 0; kh < 2; kh++)
            bOff[nf][kh] = n * 64 + (((lq + 4 * kh) ^ n7) << 3);
    }

    const f32x4 zero = {0.f, 0.f, 0.f, 0.f};
    f32x4 acc[4][4];
#pragma unroll
    for (int i = 0; i < 4; i++)
#pragma unroll
        for (int j = 0; j < 4; j++) acc[i][j] = zero;

    for (int kk = 0; kk < HD; kk += 64) {
#pragma unroll
        for (int n4 = 0; n4 < 4; n4++)
            gload16(aPtr[n4] + kk, As + n4 * 2048 + tid * 8);
#pragma unroll
        for (int n2 = 0; n2 < 2; n2++) {
            gload16(gPtr[n2] + kk, Bg + n2 * 2048 + tid * 8);
            gload16(uPtr[n2] + kk, Bu + n2 * 2048 + tid * 8);
        }
        __syncthreads();
#pragma unroll
        for (int kh = 0; kh < 2; kh++) {
            short8 aF[4], gF[2], uF[2];
#pragma unroll
            for (int i = 0; i < 4; i++) aF[i] = *(const short8*)(As + aOff[i][kh]);
#pragma unroll
            for (int nf = 0; nf < 2; nf++) {
                gF[nf] = *(const short8*)(Bg + bOff[nf][kh]);
                uF[nf] = *(const short8*)(Bu + bOff[nf][kh]);
            }
#pragma unroll
            for (int i = 0; i < 4; i++)
#pragma unroll
                for (int nf = 0; nf < 2; nf++) {
                    acc[i][nf]     = __builtin_amdgcn_mfma_f32_16x16x32_bf16(aF[i], gF[nf], acc[i][nf], 0, 0, 0);
                    acc[i][nf + 2] = __builtin_amdgcn_mfma_f32_16x16x32_bf16(aF[i], uF[nf], acc[i][nf + 2], 0, 0, 0);
                }
        }
        __syncthreads();
    }

    const int arow0 = row0 - r0base + wm * 64 + lq * 4;
#pragma unroll
    for (int i = 0; i < 4; i++) {
#pragma unroll
        for (int nf = 0; nf < 2; nf++) {
            int col = i0 + wn * 32 + nf * 16 + lm;
#pragma unroll
            for (int r = 0; r < 4; r++) {
                float g = acc[i][nf][r], u = acc[i][nf + 2][r];
                float a = (g / (1.f + __expf(-g))) * u;
                act[(long)(arow0 + i * 16 + r) * NI + col] = f2bf(a);
            }
        }
    }
}

// ---------- 5. GEMM2: rowout[row] = act[row] @ W2  (full K, NO atomics) ----------
__global__ __launch_bounds__(256) void gemm2_kernel(
    const short* __restrict__ act, const short* __restrict__ w2T,
    const int* __restrict__ ctrl, float* __restrict__ rowout, int r0base)
{
    const int row0 = r0base + blockIdx.y * 128;
    if (row0 >= ctrl[24]) return;
    int e = 0;
#pragma unroll
    for (int q = 1; q < NEXP; q++) if (row0 >= ctrl[16 + q]) e = q;
    const int n0 = blockIdx.x * 128;

    __shared__ __align__(16) short As[8192];   // [128 rows][64 k]
    __shared__ __align__(16) short Bs[8192];   // [128 n][64 k]

    const int tid = threadIdx.x;
    const int wave = tid >> 6, lane = tid & 63;
    const int lm = lane & 15, lq = lane >> 4;
    const int wm = wave >> 1, wn = wave & 1;

    const int srow = tid >> 3;
    const int xorOff = (((tid & 7) ^ (srow & 7)) << 3);
    const int arow = row0 - r0base;
    const short* aPtr[4];
    const short* bPtr[4];
    const long wb = (long)e * HD * NI;
#pragma unroll
    for (int n4 = 0; n4 < 4; n4++) {
        aPtr[n4] = act + (long)(arow + n4 * 32 + srow) * NI + xorOff;
        bPtr[n4] = w2T + wb + (long)(n0 + n4 * 32 + srow) * NI + xorOff;
    }

    int aOff[4][2], bOff[4][2];
#pragma unroll
    for (int i = 0; i < 4; i++) {
        const int r = wm * 64 + i * 16 + lm, r7 = r & 7;
        const int n = wn * 64 + i * 16 + lm, n7 = n & 7;
#pragma unroll
        for (int kh = 0; kh < 2; kh++) {
            aOff[i][kh] = r * 64 + (((lq + 4 * kh) ^ r7) << 3);
            bOff[i][kh] = n * 64 + (((lq + 4 * kh) ^ n7) << 3);
        }
    }

    const f32x4 zero = {0.f, 0.f, 0.f, 0.f};
    f32x4 acc[4][4];
#pragma unroll
    for (int i = 0; i < 4; i++)
#pragma unroll
        for (int j = 0; j < 4; j++) acc[i][j] = zero;

    for (int kk = 0; kk < NI; kk += 64) {
#pragma unroll
        for (int n4 = 0; n4 < 4; n4++) {
            gload16(aPtr[n4] + kk, As + n4 * 2048 + tid * 8);
            gload16(bPtr[n4] + kk, Bs + n4 * 2048 + tid * 8);
        }
        __syncthreads();
#pragma unroll
        for (int kh = 0; kh < 2; kh++) {
            short8 aF[4], bF[4];
#pragma unroll
            for (int i = 0; i < 4; i++) {
                aF[i] = *(const short8*)(As + aOff[i][kh]);
                bF[i] = *(const short8*)(Bs + bOff[i][kh]);
            }
#pragma unroll
            for (int i = 0; i < 4; i++)
#pragma unroll
                for (int j = 0; j < 4; j++)
                    acc[i][j] = __builtin_amdgcn_mfma_f32_16x16x32_bf16(aF[i], bF[j], acc[i][j], 0, 0, 0);
        }
        __syncthreads();
    }

    // plain fp32 stores to per-row output (each (row,col) produced by exactly one block)
    float* rp = rowout + (long)row0 * HD + n0 + wn * 64 + lm;
#pragma unroll
    for (int i = 0; i < 4; i++) {
        int rl = wm * 64 + i * 16 + lq * 4;
#pragma unroll
        for (int r = 0; r < 4; r++) {
            float* rr = rp + (long)(rl + r) * HD;
#pragma unroll
            for (int j = 0; j < 4; j++)
                rr[j * 16] = acc[i][j][r];
        }
    }
}

// ---------- 6. combine: out[t] = w0*rowout[r0] + w1*rowout[r1] ----------
__global__ __launch_bounds__(256) void combine_kernel(
    const float* __restrict__ rowout, const float* __restrict__ rows_w,
    const int* __restrict__ tok2row, void* __restrict__ dout,
    const int* __restrict__ ctrl)
{
    const int flag = ctrl[31];
    int idx = blockIdx.x * 256 + threadIdx.x;      // one thread per 8 outputs
    int t = idx >> 7, c = (idx & 127) << 3;
    int r0 = tok2row[2 * t], r1 = tok2row[2 * t + 1];
    float w0 = rows_w[r0], w1 = rows_w[r1];
    const float* p0 = rowout + (long)r0 * HD + c;
    const float* p1 = rowout + (long)r1 * HD + c;
    f32x4 a0 = *(const f32x4*)p0, a1 = *(const f32x4*)(p0 + 4);
    f32x4 b0 = *(const f32x4*)p1, b1 = *(const f32x4*)(p1 + 4);
    f32x4 o0, o1;
    o0.x = w0 * a0.x + w1 * b0.x;  o0.y = w0 * a0.y + w1 * b0.y;
    o0.z = w0 * a0.z + w1 * b0.z;  o0.w = w0 * a0.w + w1 * b0.w;
    o1.x = w0 * a1.x + w1 * b1.x;  o1.y = w0 * a1.y + w1 * b1.y;
    o1.z = w0 * a1.z + w1 * b1.z;  o1.w = w0 * a1.w + w1 * b1.w;
    if (flag) {
        float* o = (float*)dout + (long)t * HD + c;
        *(f32x4*)o = o0;
        *(f32x4*)(o + 4) = o1;
    } else {
        short8 s;
        s[0] = f2bf(o0.x); s[1] = f2bf(o0.y); s[2] = f2bf(o0.z); s[3] = f2bf(o0.w);
        s[4] = f2bf(o1.x); s[5] = f2bf(o1.y); s[6] = f2bf(o1.z); s[7] = f2bf(o1.w);
        *(short8*)((short*)dout + (long)t * HD + c) = s;
    }
}

extern "C" void kernel_launch(void* const* d_in, const int* in_sizes, int n_in,
                              void* d_out, int out_size, void* d_ws, size_t ws_size,
                              hipStream_t stream) {
    char* ws = (char*)d_ws;
    // layout: ctrl | top_i | top_w | rows_tok | rows_w | tok2row | x_bf | w1T | w2T | rowout | act(chunk)
    int*   ctrl     = (int*)ws;
    int*   top_i    = (int*)(ws + 512);
    float* top_w    = (float*)(ws + 66048);
    int*   rows_tok = (int*)(ws + 131584);
    float* rows_w   = (float*)(ws + 201216);
    int*   tok2row  = (int*)(ws + 270848);
    short* xbf      = (short*)(ws + 336384);
    short* w1T      = (short*)(ws + 17113600);    // 92,274,688 B
    short* w2T      = (short*)(ws + 109388288);   // 46,137,344 B
    float* rowout   = (float*)(ws + 155525632);   // 71,303,168 B (MAXROWS x HD fp32)
    short* act      = (short*)(ws + 226828800);   // RC * NI * 2 B

    const long act_off = 226828800L;
    long RC = ((long)ws_size - act_off) / (NI * 2);
    RC &= ~127L;
    if (RC > MAXROWS) RC = MAXROWS;
    if (RC < 128) RC = 128;
    while (RC > 128 && act_off + RC * (NI * 2) > (long)ws_size) RC -= 128;

    hipMemsetAsync(ws, 0, 512, stream);           // ctrl only

    detect_kernel<<<1, 256, 0, stream>>>((const unsigned short*)d_in[0], ctrl);
    transpose_w_kernel<<<dim3(NI2 / 64, HD / 64, NEXP), 256, 0, stream>>>(d_in[2], w1T, ctrl, HD, NI2);
    transpose_w_kernel<<<dim3(HD / 64, NI / 64, NEXP), 256, 0, stream>>>(d_in[3], w2T, ctrl, NI, HD);
    gate_kernel<<<TOK / 4, 256, 0, stream>>>(d_in[0], d_in[1], top_i, top_w, ctrl, xbf);
    offsets_pad_kernel<<<1, 256, 0, stream>>>(ctrl, rows_tok, rows_w);
    scatter_kernel<<<TOK / 256, 256, 0, stream>>>(top_i, top_w, ctrl, rows_tok, rows_w, tok2row);

    for (long r0 = 0; r0 < MAXROWS; r0 += RC) {
        long rc = MAXROWS - r0; if (rc > RC) rc = RC;
        gemm1_kernel<<<dim3(NI / 64, rc / 128), 256, 0, stream>>>(
            xbf, w1T, rows_tok, ctrl, act, (int)r0);
        gemm2_kernel<<<dim3(HD / 128, rc / 128), 256, 0, stream>>>(
            act, w2T, ctrl, rowout, (int)r0);
    }
    combine_kernel<<<TOK * HD / 8 / 256, 256, 0, stream>>>(rowout, rows_w, tok2row, d_out, ctrl);
}

// Round 6
// 1056.606 us; speedup vs baseline: 1.0632x; 1.0415x over previous
//
#include <hip/hip_runtime.h>

#define TOK   8192
#define HD    1024
#define NI    2816
#define NI2   5632
#define NEXP  8
#define MAXROWS 18432   // 16384 + 8*256 worst-case padding (expert tiles 256-aligned)

typedef __attribute__((ext_vector_type(8))) short short8;
typedef __attribute__((ext_vector_type(4))) short short4v;
typedef __attribute__((ext_vector_type(4))) float f32x4;

// ---------- helpers ----------
__device__ __forceinline__ float bf2f(short v) {
    union { unsigned u; float f; } c; c.u = ((unsigned)(unsigned short)v) << 16; return c.f;
}
__device__ __forceinline__ short f2bf(float f) {
    union { float f; unsigned u; } c; c.f = f;
    unsigned r = c.u + 0x7fff + ((c.u >> 16) & 1);   // RNE
    return (short)(r >> 16);
}
// async global->LDS, 16B per lane.
__device__ __forceinline__ void gload16(const short* g, short* l) {
    __builtin_amdgcn_global_load_lds(
        (const __attribute__((address_space(1))) void*)(g),
        (__attribute__((address_space(3))) void*)(l),
        16, 0, 0);
}

// ---------- 0. dtype detect ----------
__global__ void detect_kernel(const unsigned short* __restrict__ xs, int* __restrict__ ctrl)
{
    int bad = 0;
    for (int i = threadIdx.x; i < 4096; i += 256) {
        int e = (xs[i] >> 7) & 0xFF;
        if (e >= 137) bad = 1;
    }
    if (bad) atomicOr(&ctrl[31], 1);          // flag=1 -> inputs are fp32
}

// ---------- 0c. weight convert + TRANSPOSE: [E][rows][cols] -> [E][cols][rows] bf16 ----------
__global__ __launch_bounds__(256) void transpose_w_kernel(
    const void* __restrict__ src, short* __restrict__ dst,
    const int* __restrict__ ctrl, int rows, int cols)
{
    const int flag = ctrl[31];
    __shared__ short tile[64][66];
    const long ebase = (long)blockIdx.z * rows * cols;
    const int r0 = blockIdx.y * 64, c0 = blockIdx.x * 64;
    const int lr = threadIdx.x >> 2, lc = (threadIdx.x & 3) * 16;

    if (flag) {
        const float* s = (const float*)src + ebase + (long)(r0 + lr) * cols + c0 + lc;
#pragma unroll
        for (int j = 0; j < 16; j += 4) {
            f32x4 v = *(const f32x4*)(s + j);
            tile[lr][lc + j + 0] = f2bf(v.x);
            tile[lr][lc + j + 1] = f2bf(v.y);
            tile[lr][lc + j + 2] = f2bf(v.z);
            tile[lr][lc + j + 3] = f2bf(v.w);
        }
    } else {
        const short* s = (const short*)src + ebase + (long)(r0 + lr) * cols + c0 + lc;
#pragma unroll
        for (int j = 0; j < 16; j += 8)
            *(short8*)&tile[lr][lc + j] = *(const short8*)(s + j);
    }
    __syncthreads();
    short* d = dst + ebase + (long)(c0 + lr) * rows + r0 + lc;
    short8 o0, o1;
#pragma unroll
    for (int j = 0; j < 8; j++) o0[j] = tile[lc + j][lr];
#pragma unroll
    for (int j = 0; j < 8; j++) o1[j] = tile[lc + 8 + j][lr];
    *(short8*)(d) = o0;
    *(short8*)(d + 8) = o1;
}

// ---------- 1. gating (fused x->bf16 convert) ----------
__global__ __launch_bounds__(256) void gate_kernel(
    const void* __restrict__ xraw, const void* __restrict__ gwraw,
    int* __restrict__ top_i, float* __restrict__ top_w, int* __restrict__ ctrl,
    short* __restrict__ xbf)
{
    const int flag = ctrl[31];
    const int wave = threadIdx.x >> 6, lane = threadIdx.x & 63;
    const int t = blockIdx.x * 4 + wave;
    const float* xf = (const float*)xraw + (long)t * HD;
    const short* xs = (const short*)xraw + (long)t * HD;
    const float* gf = (const float*)gwraw;
    const short* gs = (const short*)gwraw;
    short* xo = xbf + (long)t * HD;
    float acc[NEXP] = {0.f, 0.f, 0.f, 0.f, 0.f, 0.f, 0.f, 0.f};
#pragma unroll
    for (int jj = 0; jj < 4; jj++) {
        const int i = jj * 256 + lane * 4;
        float xv0, xv1, xv2, xv3;
        if (flag) {
            f32x4 v = *(const f32x4*)(xf + i);
            xv0 = v.x; xv1 = v.y; xv2 = v.z; xv3 = v.w;
            short4v o; o.x = f2bf(xv0); o.y = f2bf(xv1); o.z = f2bf(xv2); o.w = f2bf(xv3);
            *(short4v*)(xo + i) = o;
        } else {
            short4v v = *(const short4v*)(xs + i);
            xv0 = bf2f(v.x); xv1 = bf2f(v.y); xv2 = bf2f(v.z); xv3 = bf2f(v.w);
            *(short4v*)(xo + i) = v;
        }
#pragma unroll
        for (int e = 0; e < NEXP; e++) {
            if (flag) {
                f32x4 w = *(const f32x4*)(gf + e * HD + i);
                acc[e] += xv0 * w.x + xv1 * w.y + xv2 * w.z + xv3 * w.w;
            } else {
                short4v w = *(const short4v*)(gs + e * HD + i);
                acc[e] += xv0 * bf2f(w.x) + xv1 * bf2f(w.y) + xv2 * bf2f(w.z) + xv3 * bf2f(w.w);
            }
        }
    }
#pragma unroll
    for (int e = 0; e < NEXP; e++)
        for (int off = 32; off > 0; off >>= 1) acc[e] += __shfl_down(acc[e], off, 64);
    if (lane == 0) {
        int a = 0; float va = acc[0];
#pragma unroll
        for (int e = 1; e < NEXP; e++) if (acc[e] > va) { a = e; va = acc[e]; }
        int b = -1; float vb = -1e30f;
#pragma unroll
        for (int e = 0; e < NEXP; e++) if (e != a && acc[e] > vb) { b = e; vb = acc[e]; }
        float r = __expf(vb - va);
        float wa = 1.f / (1.f + r), wb = r / (1.f + r);
        top_i[2 * t] = a;     top_w[2 * t] = wa;
        top_i[2 * t + 1] = b; top_w[2 * t + 1] = wb;
        atomicAdd(&ctrl[a], 1);
        atomicAdd(&ctrl[b], 1);
    }
}

// ---------- 2. offsets (padded to 256) + pad dummy rows ----------
__global__ void offsets_pad_kernel(int* __restrict__ ctrl,
                                   int* __restrict__ rows_tok, float* __restrict__ rows_w)
{
    __shared__ int soff[NEXP + 1];
    if (threadIdx.x == 0) {
        int off = 0;
        for (int e = 0; e < NEXP; e++) {
            soff[e] = off; ctrl[16 + e] = off;
            off += (ctrl[e] + 255) & ~255;
        }
        soff[NEXP] = off; ctrl[24] = off;
    }
    __syncthreads();
    for (int e = 0; e < NEXP; e++) {
        int c = ctrl[e];
        int start = soff[e], len = soff[e + 1] - soff[e];
        for (int s = c + (int)threadIdx.x; s < len; s += blockDim.x) {
            rows_tok[start + s] = 0;
            rows_w[start + s] = 0.f;
        }
    }
}

// ---------- 3. scatter (+ inverse map tok2row) ----------
__global__ __launch_bounds__(256) void scatter_kernel(
    const int* __restrict__ top_i, const float* __restrict__ top_w,
    int* __restrict__ ctrl, int* __restrict__ rows_tok, float* __restrict__ rows_w,
    int* __restrict__ tok2row)
{
    int t = blockIdx.x * 256 + threadIdx.x;
    if (t >= TOK) return;
#pragma unroll
    for (int k = 0; k < 2; k++) {
        int e = top_i[2 * t + k];
        int pos = atomicAdd(&ctrl[8 + e], 1);
        int row = ctrl[16 + e] + pos;
        rows_tok[row] = t;
        rows_w[row] = top_w[2 * t + k];
        tok2row[2 * t + k] = row;
    }
}

// ---------- 4. GEMM1 (4-phase, BM=256, 512 thr, counted vmcnt, dbuf) ----------
// LDS per dbuf (shorts): A rows 0-255 in 4 regions @0/4096/8192/12288,
// Bg @16384/20480, Bu @24576/28672.
// Phase-region discipline (R5 bug fix): PH0 reads A regions 0/1 (wave wm -> region wm),
// PH2 reads A regions 2/3; region residency matches the vmcnt retirement order.
__global__ __launch_bounds__(512, 2) void gemm1_kernel(
    const short* __restrict__ xbf, const short* __restrict__ w1T,
    const int* __restrict__ rows_tok, const int* __restrict__ ctrl,
    short* __restrict__ act, int r0base)
{
    const int row0 = r0base + blockIdx.y * 256;
    if (row0 >= ctrl[24]) return;
    int e = 0;
#pragma unroll
    for (int q = 1; q < NEXP; q++) if (row0 >= ctrl[16 + q]) e = q;
    const int i0 = blockIdx.x * 128;

    __shared__ __align__(16) short lds[65536];   // 128 KiB, 2 dbuf
    __shared__ int toks[256];

    const int tid = threadIdx.x;
    if (tid < 256) toks[tid] = rows_tok[row0 + tid];
    __syncthreads();

    const int wave = tid >> 6, lane = tid & 63;
    const int lm = lane & 15, lq = lane >> 4;
    const int wm = wave >> 2, wn = wave & 3;     // 2M x 4N waves

    const int srow = tid >> 3;
    const int kgS = (((tid & 7) ^ (srow & 7)) << 3);
    const short* aSrc[4];
#pragma unroll
    for (int g = 0; g < 4; g++)
        aSrc[g] = xbf + (long)toks[g * 64 + srow] * HD + kgS;
    const long wb = (long)e * NI2 * HD;
    const short* gSrc[2];
    const short* uSrc[2];
#pragma unroll
    for (int g = 0; g < 2; g++) {
        gSrc[g] = w1T + wb + (long)(i0 + g * 64 + srow) * HD + kgS;
        uSrc[g] = w1T + wb + (long)(NI + i0 + g * 64 + srow) * HD + kgS;
    }

    // per-wave rows: a<4 -> wm*64 + a*16 (regions 0/1), a>=4 -> 128 + wm*64 + (a-4)*16 (regions 2/3)
    const int swz = ((lq ^ (lm & 7)) << 3);
    int aRow[8], rbase[8];
#pragma unroll
    for (int a = 0; a < 8; a++) {
        rbase[a] = (a < 4) ? (wm * 64 + a * 16) : (128 + wm * 64 + (a - 4) * 16);
        aRow[a] = (rbase[a] + lm) * 64 + swz;
    }
    int bCol[2];
#pragma unroll
    for (int nf = 0; nf < 2; nf++) bCol[nf] = (wn * 32 + nf * 16 + lm) * 64 + swz;

    const f32x4 zero = {0.f, 0.f, 0.f, 0.f};
    f32x4 accg[8][2], accu[8][2];
#pragma unroll
    for (int a = 0; a < 8; a++)
#pragma unroll
        for (int nf = 0; nf < 2; nf++) { accg[a][nf] = zero; accu[a][nf] = zero; }

    // prologue: stage tile 0 (issue order == steady-state order), drain once
    gload16(aSrc[0], lds + tid * 8);
    gload16(aSrc[1], lds + 4096 + tid * 8);
    gload16(gSrc[0], lds + 16384 + tid * 8);
    gload16(gSrc[1], lds + 20480 + tid * 8);
    gload16(aSrc[2], lds + 8192 + tid * 8);
    gload16(aSrc[3], lds + 12288 + tid * 8);
    gload16(uSrc[0], lds + 24576 + tid * 8);
    gload16(uSrc[1], lds + 28672 + tid * 8);
    asm volatile("s_waitcnt vmcnt(0)" ::: "memory");
    __builtin_amdgcn_s_barrier();

    for (int t = 0; t < 16; t++) {
        const int bc = (t & 1) << 15;
        const int bn = bc ^ 32768;
        const int kk = t << 6;
        const int kkn = (t < 15) ? kk + 64 : kk;
        short8 aF[4][2];
        // ---- PH0: A regions 0/1 x gate. prefetch t+1 A regions 0/1 ----
        {
            short8 gF[2][2];
#pragma unroll
            for (int mf = 0; mf < 4; mf++)
#pragma unroll
                for (int ks = 0; ks < 2; ks++)
                    aF[mf][ks] = *(const short8*)(lds + bc + (aRow[mf] ^ (ks << 5)));
#pragma unroll
            for (int nf = 0; nf < 2; nf++)
#pragma unroll
                for (int ks = 0; ks < 2; ks++)
                    gF[nf][ks] = *(const short8*)(lds + bc + 16384 + (bCol[nf] ^ (ks << 5)));
            gload16(aSrc[0] + kkn, lds + bn + tid * 8);
            gload16(aSrc[1] + kkn, lds + bn + 4096 + tid * 8);
            __builtin_amdgcn_s_barrier();
            __builtin_amdgcn_s_setprio(1);
#pragma unroll
            for (int mf = 0; mf < 4; mf++)
#pragma unroll
                for (int nf = 0; nf < 2; nf++)
#pragma unroll
                    for (int ks = 0; ks < 2; ks++)
                        accg[mf][nf] = __builtin_amdgcn_mfma_f32_16x16x32_bf16(
                            aF[mf][ks], gF[nf][ks], accg[mf][nf], 0, 0, 0);
            __builtin_amdgcn_s_setprio(0);
            asm volatile("s_waitcnt vmcnt(2)" ::: "memory");   // retire cur A2/A3,Bu
            __builtin_amdgcn_s_barrier();
        }
        // ---- PH1: A regions 0/1 x up (reuse aF). prefetch t+1 Bg ----
        {
            short8 uF[2][2];
#pragma unroll
            for (int nf = 0; nf < 2; nf++)
#pragma unroll
                for (int ks = 0; ks < 2; ks++)
                    uF[nf][ks] = *(const short8*)(lds + bc + 24576 + (bCol[nf] ^ (ks << 5)));
            gload16(gSrc[0] + kkn, lds + bn + 16384 + tid * 8);
            gload16(gSrc[1] + kkn, lds + bn + 20480 + tid * 8);
            __builtin_amdgcn_s_barrier();
            __builtin_amdgcn_s_setprio(1);
#pragma unroll
            for (int mf = 0; mf < 4; mf++)
#pragma unroll
                for (int nf = 0; nf < 2; nf++)
#pragma unroll
                    for (int ks = 0; ks < 2; ks++)
                        accu[mf][nf] = __builtin_amdgcn_mfma_f32_16x16x32_bf16(
                            aF[mf][ks], uF[nf][ks], accu[mf][nf], 0, 0, 0);
            __builtin_amdgcn_s_setprio(0);
            __builtin_amdgcn_s_barrier();
        }
        // ---- PH2: A regions 2/3 x gate. prefetch t+1 A regions 2/3 ----
        {
            short8 gF[2][2];
#pragma unroll
            for (int mf = 0; mf < 4; mf++)
#pragma unroll
                for (int ks = 0; ks < 2; ks++)
                    aF[mf][ks] = *(const short8*)(lds + bc + (aRow[4 + mf] ^ (ks << 5)));
#pragma unroll
            for (int nf = 0; nf < 2; nf++)
#pragma unroll
                for (int ks = 0; ks < 2; ks++)
                    gF[nf][ks] = *(const short8*)(lds + bc + 16384 + (bCol[nf] ^ (ks << 5)));
            gload16(aSrc[2] + kkn, lds + bn + 8192 + tid * 8);
            gload16(aSrc[3] + kkn, lds + bn + 12288 + tid * 8);
            __builtin_amdgcn_s_barrier();
            __builtin_amdgcn_s_setprio(1);
#pragma unroll
            for (int mf = 0; mf < 4; mf++)
#pragma unroll
                for (int nf = 0; nf < 2; nf++)
#pragma unroll
                    for (int ks = 0; ks < 2; ks++)
                        accg[4 + mf][nf] = __builtin_amdgcn_mfma_f32_16x16x32_bf16(
                            aF[mf][ks], gF[nf][ks], accg[4 + mf][nf], 0, 0, 0);
            __builtin_amdgcn_s_setprio(0);
            __builtin_amdgcn_s_barrier();
        }
        // ---- PH3: A regions 2/3 x up (reuse aF). prefetch t+1 Bu. vmcnt(4) ----
        {
            short8 uF[2][2];
#pragma unroll
            for (int nf = 0; nf < 2; nf++)
#pragma unroll
                for (int ks = 0; ks < 2; ks++)
                    uF[nf][ks] = *(const short8*)(lds + bc + 24576 + (bCol[nf] ^ (ks << 5)));
            gload16(uSrc[0] + kkn, lds + bn + 24576 + tid * 8);
            gload16(uSrc[1] + kkn, lds + bn + 28672 + tid * 8);
            __builtin_amdgcn_s_barrier();
            __builtin_amdgcn_s_setprio(1);
#pragma unroll
            for (int mf = 0; mf < 4; mf++)
#pragma unroll
                for (int nf = 0; nf < 2; nf++)
#pragma unroll
                    for (int ks = 0; ks < 2; ks++)
                        accu[4 + mf][nf] = __builtin_amdgcn_mfma_f32_16x16x32_bf16(
                            aF[mf][ks], uF[nf][ks], accu[4 + mf][nf], 0, 0, 0);
            __builtin_amdgcn_s_setprio(0);
            asm volatile("s_waitcnt vmcnt(4)" ::: "memory");   // retire next A0/A1,Bg
            __builtin_amdgcn_s_barrier();
        }
    }

    const int arow_blk = row0 - r0base;
#pragma unroll
    for (int a = 0; a < 8; a++) {
#pragma unroll
        for (int nf = 0; nf < 2; nf++) {
            const int col = i0 + wn * 32 + nf * 16 + lm;
#pragma unroll
            for (int r = 0; r < 4; r++) {
                float g = accg[a][nf][r], u = accu[a][nf][r];
                float v = (g / (1.f + __expf(-g))) * u;
                act[(long)(arow_blk + rbase[a] + lq * 4 + r) * NI + col] = f2bf(v);
            }
        }
    }
}

// ---------- 5. GEMM2 (2-phase/K-tile, BM=256, 512 thr, counted vmcnt, dbuf) ----------
// LDS per dbuf (shorts): A regions @0/4096/8192/12288, B @16384/20480.
// PH0 reads A regions 0/1 (wave wm -> region wm); PH1 reads regions 2/3.
__global__ __launch_bounds__(512, 2) void gemm2_kernel(
    const short* __restrict__ act, const short* __restrict__ w2T,
    const int* __restrict__ ctrl, float* __restrict__ rowout, int r0base)
{
    const int row0 = r0base + blockIdx.y * 256;
    if (row0 >= ctrl[24]) return;
    int e = 0;
#pragma unroll
    for (int q = 1; q < NEXP; q++) if (row0 >= ctrl[16 + q]) e = q;
    const int n0 = blockIdx.x * 128;

    __shared__ __align__(16) short lds[49152];   // 96 KiB, 2 dbuf

    const int tid = threadIdx.x;
    const int wave = tid >> 6, lane = tid & 63;
    const int lm = lane & 15, lq = lane >> 4;
    const int wm = wave >> 2, wn = wave & 3;

    const int srow = tid >> 3;
    const int kgS = (((tid & 7) ^ (srow & 7)) << 3);
    const int arow = row0 - r0base;
    const short* aSrc[4];
#pragma unroll
    for (int g = 0; g < 4; g++)
        aSrc[g] = act + (long)(arow + g * 64 + srow) * NI + kgS;
    const long wbs = (long)e * HD * NI;
    const short* bSrc[2];
#pragma unroll
    for (int g = 0; g < 2; g++)
        bSrc[g] = w2T + wbs + (long)(n0 + g * 64 + srow) * NI + kgS;

    const int swz = ((lq ^ (lm & 7)) << 3);
    int aRow[8], rbase[8];
#pragma unroll
    for (int a = 0; a < 8; a++) {
        rbase[a] = (a < 4) ? (wm * 64 + a * 16) : (128 + wm * 64 + (a - 4) * 16);
        aRow[a] = (rbase[a] + lm) * 64 + swz;
    }
    int bCol[2];
#pragma unroll
    for (int nf = 0; nf < 2; nf++) bCol[nf] = (wn * 32 + nf * 16 + lm) * 64 + swz;

    const f32x4 zero = {0.f, 0.f, 0.f, 0.f};
    f32x4 acc[8][2];
#pragma unroll
    for (int a = 0; a < 8; a++)
#pragma unroll
        for (int nf = 0; nf < 2; nf++) acc[a][nf] = zero;

    // prologue (issue order == steady-state order)
    gload16(aSrc[0], lds + tid * 8);
    gload16(aSrc[1], lds + 4096 + tid * 8);
    gload16(bSrc[0], lds + 16384 + tid * 8);
    gload16(bSrc[1], lds + 20480 + tid * 8);
    gload16(aSrc[2], lds + 8192 + tid * 8);
    gload16(aSrc[3], lds + 12288 + tid * 8);
    asm volatile("s_waitcnt vmcnt(0)" ::: "memory");
    __builtin_amdgcn_s_barrier();

    for (int t = 0; t < 44; t++) {               // NI/64
        const int bc = (t & 1) * 24576;
        const int bn = bc ^ 24576;
        const int kk = t << 6;
        const int kkn = (t < 43) ? kk + 64 : kk;
        short8 bF[2][2];
        // ---- PH0: A regions 0/1. prefetch t+1 A0/A1 + B ----
        {
            short8 aF[4][2];
#pragma unroll
            for (int mf = 0; mf < 4; mf++)
#pragma unroll
                for (int ks = 0; ks < 2; ks++)
                    aF[mf][ks] = *(const short8*)(lds + bc + (aRow[mf] ^ (ks << 5)));
#pragma unroll
            for (int nf = 0; nf < 2; nf++)
#pragma unroll
                for (int ks = 0; ks < 2; ks++)
                    bF[nf][ks] = *(const short8*)(lds + bc + 16384 + (bCol[nf] ^ (ks << 5)));
            gload16(aSrc[0] + kkn, lds + bn + tid * 8);
            gload16(aSrc[1] + kkn, lds + bn + 4096 + tid * 8);
            gload16(bSrc[0] + kkn, lds + bn + 16384 + tid * 8);
            gload16(bSrc[1] + kkn, lds + bn + 20480 + tid * 8);
            __builtin_amdgcn_s_barrier();
            __builtin_amdgcn_s_setprio(1);
#pragma unroll
            for (int mf = 0; mf < 4; mf++)
#pragma unroll
                for (int nf = 0; nf < 2; nf++)
#pragma unroll
                    for (int ks = 0; ks < 2; ks++)
                        acc[mf][nf] = __builtin_amdgcn_mfma_f32_16x16x32_bf16(
                            aF[mf][ks], bF[nf][ks], acc[mf][nf], 0, 0, 0);
            __builtin_amdgcn_s_setprio(0);
            asm volatile("s_waitcnt vmcnt(4)" ::: "memory");   // retire cur A2/A3
            __builtin_amdgcn_s_barrier();
        }
        // ---- PH1: A regions 2/3 (reuse bF). prefetch t+1 A2/A3 ----
        {
            short8 aF[4][2];
#pragma unroll
            for (int mf = 0; mf < 4; mf++)
#pragma unroll
                for (int ks = 0; ks < 2; ks++)
                    aF[mf][ks] = *(const short8*)(lds + bc + (aRow[4 + mf] ^ (ks << 5)));
            gload16(aSrc[2] + kkn, lds + bn + 8192 + tid * 8);
            gload16(aSrc[3] + kkn, lds + bn + 12288 + tid * 8);
            __builtin_amdgcn_s_barrier();
            __builtin_amdgcn_s_setprio(1);
#pragma unroll
            for (int mf = 0; mf < 4; mf++)
#pragma unroll
                for (int nf = 0; nf < 2; nf++)
#pragma unroll
                    for (int ks = 0; ks < 2; ks++)
                        acc[4 + mf][nf] = __builtin_amdgcn_mfma_f32_16x16x32_bf16(
                            aF[mf][ks], bF[nf][ks], acc[4 + mf][nf], 0, 0, 0);
            __builtin_amdgcn_s_setprio(0);
            asm volatile("s_waitcnt vmcnt(2)" ::: "memory");   // retire next A0/A1,B
            __builtin_amdgcn_s_barrier();
        }
    }

    float* rp = rowout + (long)row0 * HD + n0 + wn * 32 + lm;
#pragma unroll
    for (int a = 0; a < 8; a++) {
        const int rl = rbase[a] + lq * 4;
#pragma unroll
        for (int r = 0; r < 4; r++) {
            float* rr = rp + (long)(rl + r) * HD;
#pragma unroll
            for (int nf = 0; nf < 2; nf++)
                rr[nf * 16] = acc[a][nf][r];
        }
    }
}

// ---------- 6. combine: out[t] = w0*rowout[r0] + w1*rowout[r1] ----------
__global__ __launch_bounds__(256) void combine_kernel(
    const float* __restrict__ rowout, const float* __restrict__ rows_w,
    const int* __restrict__ tok2row, void* __restrict__ dout,
    const int* __restrict__ ctrl)
{
    const int flag = ctrl[31];
    int idx = blockIdx.x * 256 + threadIdx.x;
    int t = idx >> 7, c = (idx & 127) << 3;
    int r0 = tok2row[2 * t], r1 = tok2row[2 * t + 1];
    float w0 = rows_w[r0], w1 = rows_w[r1];
    const float* p0 = rowout + (long)r0 * HD + c;
    const float* p1 = rowout + (long)r1 * HD + c;
    f32x4 a0 = *(const f32x4*)p0, a1 = *(const f32x4*)(p0 + 4);
    f32x4 b0 = *(const f32x4*)p1, b1 = *(const f32x4*)(p1 + 4);
    f32x4 o0, o1;
    o0.x = w0 * a0.x + w1 * b0.x;  o0.y = w0 * a0.y + w1 * b0.y;
    o0.z = w0 * a0.z + w1 * b0.z;  o0.w = w0 * a0.w + w1 * b0.w;
    o1.x = w0 * a1.x + w1 * b1.x;  o1.y = w0 * a1.y + w1 * b1.y;
    o1.z = w0 * a1.z + w1 * b1.z;  o1.w = w0 * a1.w + w1 * b1.w;
    if (flag) {
        float* o = (float*)dout + (long)t * HD + c;
        *(f32x4*)o = o0;
        *(f32x4*)(o + 4) = o1;
    } else {
        short8 s;
        s[0] = f2bf(o0.x); s[1] = f2bf(o0.y); s[2] = f2bf(o0.z); s[3] = f2bf(o0.w);
        s[4] = f2bf(o1.x); s[5] = f2bf(o1.y); s[6] = f2bf(o1.z); s[7] = f2bf(o1.w);
        *(short8*)((short*)dout + (long)t * HD + c) = s;
    }
}

extern "C" void kernel_launch(void* const* d_in, const int* in_sizes, int n_in,
                              void* d_out, int out_size, void* d_ws, size_t ws_size,
                              hipStream_t stream) {
    char* ws = (char*)d_ws;
    // layout: ctrl | top_i | top_w | rows_tok | rows_w | tok2row | x_bf | w1T | w2T | rowout | act(chunk)
    int*   ctrl     = (int*)ws;
    int*   top_i    = (int*)(ws + 512);
    float* top_w    = (float*)(ws + 66048);
    int*   rows_tok = (int*)(ws + 131584);
    float* rows_w   = (float*)(ws + 205312);
    int*   tok2row  = (int*)(ws + 279040);
    short* xbf      = (short*)(ws + 344576);
    short* w1T      = (short*)(ws + 17121792);    // 92,274,688 B
    short* w2T      = (short*)(ws + 109396480);   // 46,137,344 B
    float* rowout   = (float*)(ws + 155533824);   // 75,497,472 B (MAXROWS x HD fp32)
    short* act      = (short*)(ws + 231031296);   // RC * NI * 2 B

    const long act_off = 231031296L;
    long RC = ((long)ws_size - act_off) / (NI * 2);
    RC &= ~255L;
    if (RC > MAXROWS) RC = MAXROWS;
    if (RC < 256) RC = 256;
    while (RC > 256 && act_off + RC * (NI * 2) > (long)ws_size) RC -= 256;

    hipMemsetAsync(ws, 0, 512, stream);           // ctrl only

    detect_kernel<<<1, 256, 0, stream>>>((const unsigned short*)d_in[0], ctrl);
    transpose_w_kernel<<<dim3(NI2 / 64, HD / 64, NEXP), 256, 0, stream>>>(d_in[2], w1T, ctrl, HD, NI2);
    transpose_w_kernel<<<dim3(HD / 64, NI / 64, NEXP), 256, 0, stream>>>(d_in[3], w2T, ctrl, NI, HD);
    gate_kernel<<<TOK / 4, 256, 0, stream>>>(d_in[0], d_in[1], top_i, top_w, ctrl, xbf);
    offsets_pad_kernel<<<1, 256, 0, stream>>>(ctrl, rows_tok, rows_w);
    scatter_kernel<<<TOK / 256, 256, 0, stream>>>(top_i, top_w, ctrl, rows_tok, rows_w, tok2row);

    for (long r0 = 0; r0 < MAXROWS; r0 += RC) {
        long rc = MAXROWS - r0; if (rc > RC) rc = RC;
        gemm1_kernel<<<dim3(NI / 128, rc / 256), 512, 0, stream>>>(
            xbf, w1T, rows_tok, ctrl, act, (int)r0);
        gemm2_kernel<<<dim3(HD / 128, rc / 256), 512, 0, stream>>>(
            act, w2T, ctrl, rowout, (int)r0);
    }
    combine_kernel<<<TOK * HD / 8 / 256, 256, 0, stream>>>(rowout, rows_w, tok2row, d_out, ctrl);
}